// Round 1
// baseline (301.365 us; speedup 1.0000x reference)
//
#include <hip/hip_runtime.h>

typedef __attribute__((ext_vector_type(8))) __bf16 bf16x8;
typedef __attribute__((ext_vector_type(4))) float f32x4;

#define DEVINL __device__ __forceinline__

constexpr int BZ = 4;
constexpr int SEQ = 1024;
constexpr int DMODEL = 1024;
constexpr int NH = 16;
constexpr int HD = 64;               // dk = dv = 64
constexpr int MSLOT = 128;
constexpr int NT = BZ * SEQ;         // 4096 tokens
constexpr int SKM = SEQ + MSLOT;     // 1152 keys per batch
constexpr int VT_LD = BZ * SKM;      // 4608: leading dim of global V^T
constexpr float SCALE_M = 11.313708498984761f;   // sqrt(128)
constexpr float SC_SCALE = 0.125f;               // 1/sqrt(dk)
constexpr float LOG2E = 1.4426950408889634f;

// workspace offsets in bf16 (ushort) elements
constexpr size_t OF_QIN  = 0;
constexpr size_t OF_KIN  = OF_QIN  + (size_t)NT * DMODEL;
constexpr size_t OF_VIN  = OF_KIN  + (size_t)NT * DMODEL;
constexpr size_t OF_WQT  = OF_VIN  + (size_t)NT * DMODEL;
constexpr size_t OF_WKT  = OF_WQT  + (size_t)DMODEL * DMODEL;
constexpr size_t OF_WVT  = OF_WKT  + (size_t)DMODEL * DMODEL;
constexpr size_t OF_WOT  = OF_WVT  + (size_t)DMODEL * DMODEL;
constexpr size_t OF_QB   = OF_WOT  + (size_t)DMODEL * DMODEL;
constexpr size_t OF_KPR  = OF_QB   + (size_t)NT * DMODEL;
constexpr size_t OF_KMEM = OF_KPR  + (size_t)NT * DMODEL;
constexpr size_t OF_VTG  = OF_KMEM + (size_t)MSLOT * DMODEL;
constexpr size_t OF_AOUT = OF_VTG  + (size_t)DMODEL * VT_LD;
// total = 34209792 ushorts = ~65.3 MB of ws

DEVINL unsigned short f2bf(float f) {
  union { float f; unsigned u; } v; v.f = f;
  unsigned r = v.u + 0x7FFF + ((v.u >> 16) & 1);   // RNE
  return (unsigned short)(r >> 16);
}

DEVINL f32x4 mfma16(bf16x8 a, bf16x8 b, f32x4 c) {
  return __builtin_amdgcn_mfma_f32_16x16x32_bf16(a, b, c, 0, 0, 0);
}

DEVINL float redmax16(float v) {
  v = fmaxf(v, __shfl_xor(v, 1, 16));
  v = fmaxf(v, __shfl_xor(v, 2, 16));
  v = fmaxf(v, __shfl_xor(v, 4, 16));
  v = fmaxf(v, __shfl_xor(v, 8, 16));
  return v;
}
DEVINL float redsum16(float v) {
  v += __shfl_xor(v, 1, 16);
  v += __shfl_xor(v, 2, 16);
  v += __shfl_xor(v, 4, 16);
  v += __shfl_xor(v, 8, 16);
  return v;
}

// ---------------- conversion kernels ----------------

__global__ __launch_bounds__(256) void cvt_bf16(const float* __restrict__ src,
                                                unsigned short* __restrict__ dst, int n) {
  int i = (blockIdx.x * 256 + threadIdx.x) * 8;
  if (i >= n) return;
  float4 v0 = *(const float4*)(src + i);
  float4 v1 = *(const float4*)(src + i + 4);
  union { unsigned short u[8]; uint4 v; } o;
  o.u[0] = f2bf(v0.x); o.u[1] = f2bf(v0.y); o.u[2] = f2bf(v0.z); o.u[3] = f2bf(v0.w);
  o.u[4] = f2bf(v1.x); o.u[5] = f2bf(v1.y); o.u[6] = f2bf(v1.z); o.u[7] = f2bf(v1.w);
  *(uint4*)(dst + i) = o.v;
}

// W [K=1024][N=1024] fp32 -> Wt [N][K] bf16 (tiled transpose)
__global__ __launch_bounds__(256) void transpose_cvt(const float* __restrict__ src,
                                                     unsigned short* __restrict__ dst) {
  __shared__ float t[32][33];
  const int tx = threadIdx.x, ty = threadIdx.y;
  const int n0 = blockIdx.x * 32, k0 = blockIdx.y * 32;
#pragma unroll
  for (int r = 0; r < 4; ++r)
    t[ty + r * 8][tx] = src[(size_t)(k0 + ty + r * 8) * DMODEL + n0 + tx];
  __syncthreads();
#pragma unroll
  for (int r = 0; r < 4; ++r)
    dst[(size_t)(n0 + ty + r * 8) * DMODEL + k0 + tx] = f2bf(t[tx][ty + r * 8]);
}

// Kmem[j][c] = bf16(mk[j][c] * sqrt(M)), 128x1024 elementwise
__global__ __launch_bounds__(256) void kmem_cvt(const float* __restrict__ mk,
                                                unsigned short* __restrict__ dst) {
  int i = blockIdx.x * 256 + threadIdx.x;   // < 131072
  dst[i] = f2bf(mk[i] * SCALE_M);
}

// mv [128][1024] -> VtG[c][b*1152 + 1024 + j] = bf16(mv[j][c]*sqrt(M)) for b in 0..3
__global__ __launch_bounds__(256) void vmem_transpose(const float* __restrict__ mv,
                                                      unsigned short* __restrict__ VtG) {
  __shared__ float t[32][33];
  const int tx = threadIdx.x, ty = threadIdx.y;
  const int j0 = blockIdx.x * 32, c0 = blockIdx.y * 32;
#pragma unroll
  for (int r = 0; r < 4; ++r)
    t[ty + r * 8][tx] = mv[(size_t)(j0 + ty + r * 8) * DMODEL + c0 + tx];
  __syncthreads();
#pragma unroll
  for (int r = 0; r < 4; ++r) {
    int c = c0 + ty + r * 8;
    unsigned short v = f2bf(t[tx][ty + r * 8] * SCALE_M);
#pragma unroll
    for (int bb = 0; bb < BZ; ++bb)
      VtG[(size_t)c * VT_LD + bb * SKM + SEQ + j0 + tx] = v;
  }
}

// ---------------- GEMM: C[M][1024] = A[M][1024] @ Wt[n][k]^T + bias ----------------
// BM=128 BN=64 BK=32, 4 waves 2x2, wave tile 64x32 (4x2 MFMAs of 16x16x32).
// LDS rows padded to 40 bf16 (80B, 16B-aligned, 2-way bank aliasing = free).
template <int OUT_F32>
__global__ __launch_bounds__(256) void gemm_bt(const unsigned short* __restrict__ A,
                                               const unsigned short* __restrict__ Wt,
                                               const float* __restrict__ bias,
                                               void* __restrict__ Cout) {
  __shared__ unsigned short As[128 * 40];
  __shared__ unsigned short Bs[64 * 40];
  const int tid = threadIdx.x;
  const int m0 = blockIdx.y * 128;
  const int n0 = blockIdx.x * 64;
  const int w = tid >> 6, lane = tid & 63, quad = lane >> 4, l16 = lane & 15;
  const int wr = w >> 1, wc = w & 1;
  f32x4 acc[4][2] = {};
  for (int kt = 0; kt < 32; ++kt) {
    const int k0 = kt * 32;
#pragma unroll
    for (int gi = 0; gi < 2; ++gi) {
      int g = tid + gi * 256;               // A tile: 512 granules of 16B
      int row = g >> 2, slot = g & 3;
      uint4 v = *(const uint4*)(A + (size_t)(m0 + row) * DMODEL + k0 + slot * 8);
      *(uint4*)(As + row * 40 + slot * 8) = v;
    }
    {
      int row = tid >> 2, slot = tid & 3;   // B tile: 256 granules
      uint4 v = *(const uint4*)(Wt + (size_t)(n0 + row) * DMODEL + k0 + slot * 8);
      *(uint4*)(Bs + row * 40 + slot * 8) = v;
    }
    __syncthreads();
    bf16x8 af[4], bfr[2];
#pragma unroll
    for (int rb = 0; rb < 4; ++rb)
      af[rb] = *(const bf16x8*)(As + (wr * 64 + rb * 16 + l16) * 40 + quad * 8);
#pragma unroll
    for (int cb = 0; cb < 2; ++cb)
      bfr[cb] = *(const bf16x8*)(Bs + (wc * 32 + cb * 16 + l16) * 40 + quad * 8);
#pragma unroll
    for (int rb = 0; rb < 4; ++rb)
#pragma unroll
      for (int cb = 0; cb < 2; ++cb)
        acc[rb][cb] = mfma16(af[rb], bfr[cb], acc[rb][cb]);
    __syncthreads();
  }
#pragma unroll
  for (int rb = 0; rb < 4; ++rb)
#pragma unroll
    for (int cb = 0; cb < 2; ++cb)
#pragma unroll
      for (int r = 0; r < 4; ++r) {
        int row = m0 + wr * 64 + rb * 16 + quad * 4 + r;   // D: row=(lane>>4)*4+reg
        int col = n0 + wc * 32 + cb * 16 + l16;            //    col=lane&15
        float v = acc[rb][cb][r] + bias[col];
        if (OUT_F32) ((float*)Cout)[(size_t)row * DMODEL + col] = v;
        else ((unsigned short*)Cout)[(size_t)row * DMODEL + col] = f2bf(v);
      }
}

// V projection writing V^T: VtG[n][tokcol] = (values @ Wvt^T + bv)^T, tokcol = tok + (tok>>10)*128
// Roles swapped: A-operand = Wt rows (n x k), B-operand = values rows (tok x k).
__global__ __launch_bounds__(256) void gemm_bt_vt(const unsigned short* __restrict__ A,
                                                  const unsigned short* __restrict__ Wt,
                                                  const float* __restrict__ bias,
                                                  unsigned short* __restrict__ VtG) {
  __shared__ unsigned short Ts[64 * 40];    // token rows
  __shared__ unsigned short Ns[128 * 40];   // n rows
  const int tid = threadIdx.x;
  const int t0 = blockIdx.x * 64;           // token tile
  const int n0 = blockIdx.y * 128;          // n tile
  const int w = tid >> 6, lane = tid & 63, quad = lane >> 4, l16 = lane & 15;
  const int wr = w >> 1, wc = w & 1;
  f32x4 acc[4][2] = {};
  for (int kt = 0; kt < 32; ++kt) {
    const int k0 = kt * 32;
    {
      int row = tid >> 2, slot = tid & 3;
      uint4 v = *(const uint4*)(A + (size_t)(t0 + row) * DMODEL + k0 + slot * 8);
      *(uint4*)(Ts + row * 40 + slot * 8) = v;
    }
#pragma unroll
    for (int gi = 0; gi < 2; ++gi) {
      int g = tid + gi * 256;
      int row = g >> 2, slot = g & 3;
      uint4 v = *(const uint4*)(Wt + (size_t)(n0 + row) * DMODEL + k0 + slot * 8);
      *(uint4*)(Ns + row * 40 + slot * 8) = v;
    }
    __syncthreads();
    bf16x8 af[4], bfr[2];
#pragma unroll
    for (int rb = 0; rb < 4; ++rb)
      af[rb] = *(const bf16x8*)(Ns + (wr * 64 + rb * 16 + l16) * 40 + quad * 8);
#pragma unroll
    for (int cb = 0; cb < 2; ++cb)
      bfr[cb] = *(const bf16x8*)(Ts + (wc * 32 + cb * 16 + l16) * 40 + quad * 8);
#pragma unroll
    for (int rb = 0; rb < 4; ++rb)
#pragma unroll
      for (int cb = 0; cb < 2; ++cb)
        acc[rb][cb] = mfma16(af[rb], bfr[cb], acc[rb][cb]);
    __syncthreads();
  }
#pragma unroll
  for (int rb = 0; rb < 4; ++rb)
#pragma unroll
    for (int cb = 0; cb < 2; ++cb)
#pragma unroll
      for (int r = 0; r < 4; ++r) {
        int n = n0 + wr * 64 + rb * 16 + quad * 4 + r;
        int tok = t0 + wc * 32 + cb * 16 + l16;
        int col = tok + (tok >> 10) * MSLOT;   // batch-concat column remap
        VtG[(size_t)n * VT_LD + col] = f2bf(acc[rb][cb][r] + bias[n]);
      }
}

// ---------------- flash attention ----------------
// grid (qb=16, h=16, b=4), 256 threads = 4 waves, 64 queries/block (16 per wave).
// 18 key tiles of 64: tiles 0..15 from Kproj/VtG token cols, 16..17 from memory slots.
__global__ __launch_bounds__(256) void attn_kernel(const unsigned short* __restrict__ Qb,
                                                   const unsigned short* __restrict__ Kproj,
                                                   const unsigned short* __restrict__ Kmem,
                                                   const unsigned short* __restrict__ VtG,
                                                   unsigned short* __restrict__ Aout) {
  __shared__ unsigned short Ks[64 * 72];        // [key][kd], stride 72 (144B, 16B-aligned)
  __shared__ unsigned short Vs[64 * 72];        // [dv][key] (V^T tile)
  __shared__ unsigned short Pl[4 * 16 * 72];    // per-wave P round-trip
  const int tid = threadIdx.x;
  const int qb = blockIdx.x, h = blockIdx.y, b = blockIdx.z;
  const int w = tid >> 6, lane = tid & 63, quad = lane >> 4, l16 = lane & 15;
  const int token0 = b * SEQ + qb * 64 + w * 16;
  unsigned short* Pw = Pl + w * 16 * 72;

  bf16x8 qf[2];   // A-operand: Q[q=l16][kd = quad*8+j (+32t)]
#pragma unroll
  for (int t = 0; t < 2; ++t)
    qf[t] = *(const bf16x8*)(Qb + (size_t)(token0 + l16) * DMODEL + h * HD + t * 32 + quad * 8);

  f32x4 O[4] = {};
  float m[4], l[4];
#pragma unroll
  for (int r = 0; r < 4; ++r) { m[r] = -1e30f; l[r] = 0.0f; }

  for (int tile = 0; tile < 18; ++tile) {
    const unsigned short* ksrc;
    const unsigned short* vsrc;
    if (tile < 16) {
      ksrc = Kproj + (size_t)(b * SEQ + tile * 64) * DMODEL + h * HD;
      vsrc = VtG + (size_t)(h * HD) * VT_LD + b * SKM + tile * 64;
    } else {
      ksrc = Kmem + (size_t)((tile - 16) * 64) * DMODEL + h * HD;
      vsrc = VtG + (size_t)(h * HD) * VT_LD + b * SKM + SEQ + (tile - 16) * 64;
    }
#pragma unroll
    for (int gi = 0; gi < 2; ++gi) {
      int g = tid + gi * 256;              // 512 granules each for K and Vt tiles
      int row = g >> 3, slot = g & 7;
      *(uint4*)(Ks + row * 72 + slot * 8) = *(const uint4*)(ksrc + (size_t)row * DMODEL + slot * 8);
      *(uint4*)(Vs + row * 72 + slot * 8) = *(const uint4*)(vsrc + (size_t)row * VT_LD + slot * 8);
    }
    __syncthreads();

    // scores: S[16q x 64key] per wave, 4 key chunks of 16
    f32x4 sc[4] = {};
#pragma unroll
    for (int c = 0; c < 4; ++c)
#pragma unroll
      for (int t = 0; t < 2; ++t) {
        bf16x8 kb = *(const bf16x8*)(Ks + (c * 16 + l16) * 72 + t * 32 + quad * 8);
        sc[c] = mfma16(qf[t], kb, sc[c]);
      }

    // online softmax (rows = quad*4 + r)
    float p[4][4], mt[4];
#pragma unroll
    for (int r = 0; r < 4; ++r) mt[r] = -1e30f;
#pragma unroll
    for (int c = 0; c < 4; ++c)
#pragma unroll
      for (int r = 0; r < 4; ++r) {
        float s = sc[c][r] * SC_SCALE;
        p[c][r] = s;
        mt[r] = fmaxf(mt[r], s);
      }
#pragma unroll
    for (int r = 0; r < 4; ++r) mt[r] = redmax16(mt[r]);
    float alpha[4], rs[4];
#pragma unroll
    for (int r = 0; r < 4; ++r) {
      float mn = fmaxf(m[r], mt[r]);
      alpha[r] = exp2f((m[r] - mn) * LOG2E);
      m[r] = mn;
      rs[r] = 0.0f;
    }
#pragma unroll
    for (int c = 0; c < 4; ++c)
#pragma unroll
      for (int r = 0; r < 4; ++r) {
        float e = exp2f((p[c][r] - m[r]) * LOG2E);
        p[c][r] = e;
        rs[r] += e;
      }
#pragma unroll
    for (int r = 0; r < 4; ++r) {
      rs[r] = redsum16(rs[r]);
      l[r] = l[r] * alpha[r] + rs[r];
    }
    // P: C/D layout -> LDS -> A-operand layout (wave-local; DS ops in-order per wave)
#pragma unroll
    for (int c = 0; c < 4; ++c)
#pragma unroll
      for (int r = 0; r < 4; ++r)
        Pw[(quad * 4 + r) * 72 + c * 16 + l16] = f2bf(p[c][r]);
#pragma unroll
    for (int c2 = 0; c2 < 4; ++c2)
#pragma unroll
      for (int r = 0; r < 4; ++r) O[c2][r] *= alpha[r];
#pragma unroll
    for (int t = 0; t < 2; ++t) {
      bf16x8 pa = *(const bf16x8*)(Pw + l16 * 72 + t * 32 + quad * 8);
#pragma unroll
      for (int c2 = 0; c2 < 4; ++c2) {
        bf16x8 vb = *(const bf16x8*)(Vs + (c2 * 16 + l16) * 72 + t * 32 + quad * 8);
        O[c2] = mfma16(pa, vb, O[c2]);
      }
    }
    __syncthreads();
  }

  float inv[4];
#pragma unroll
  for (int r = 0; r < 4; ++r) inv[r] = 1.0f / l[r];
#pragma unroll
  for (int c2 = 0; c2 < 4; ++c2)
#pragma unroll
    for (int r = 0; r < 4; ++r)
      Aout[(size_t)(token0 + quad * 4 + r) * DMODEL + h * HD + c2 * 16 + l16] =
          f2bf(O[c2][r] * inv[r]);
}

// ---------------- launch ----------------
extern "C" void kernel_launch(void* const* d_in, const int* in_sizes, int n_in,
                              void* d_out, int out_size, void* d_ws, size_t ws_size,
                              hipStream_t stream) {
  const float* queries = (const float*)d_in[0];
  const float* keys    = (const float*)d_in[1];
  const float* values  = (const float*)d_in[2];
  const float* Wq = (const float*)d_in[3];
  const float* bq = (const float*)d_in[4];
  const float* Wk = (const float*)d_in[5];
  const float* bk = (const float*)d_in[6];
  const float* Wv = (const float*)d_in[7];
  const float* bv = (const float*)d_in[8];
  const float* Wo = (const float*)d_in[9];
  const float* bo = (const float*)d_in[10];
  const float* mk = (const float*)d_in[11];
  const float* mv = (const float*)d_in[12];

  unsigned short* ws = (unsigned short*)d_ws;
  unsigned short* Qin  = ws + OF_QIN;
  unsigned short* Kin  = ws + OF_KIN;
  unsigned short* Vin  = ws + OF_VIN;
  unsigned short* Wqt  = ws + OF_WQT;
  unsigned short* Wkt  = ws + OF_WKT;
  unsigned short* Wvt  = ws + OF_WVT;
  unsigned short* Wot  = ws + OF_WOT;
  unsigned short* Qbp  = ws + OF_QB;
  unsigned short* Kprp = ws + OF_KPR;
  unsigned short* Kmm  = ws + OF_KMEM;
  unsigned short* VtGp = ws + OF_VTG;
  unsigned short* Aoutp = ws + OF_AOUT;

  const int nAct = NT * DMODEL;   // 4194304
  cvt_bf16<<<nAct / (256 * 8), 256, 0, stream>>>(queries, Qin, nAct);
  cvt_bf16<<<nAct / (256 * 8), 256, 0, stream>>>(keys, Kin, nAct);
  cvt_bf16<<<nAct / (256 * 8), 256, 0, stream>>>(values, Vin, nAct);

  dim3 tb(32, 8);
  transpose_cvt<<<dim3(32, 32), tb, 0, stream>>>(Wq, Wqt);
  transpose_cvt<<<dim3(32, 32), tb, 0, stream>>>(Wk, Wkt);
  transpose_cvt<<<dim3(32, 32), tb, 0, stream>>>(Wv, Wvt);
  transpose_cvt<<<dim3(32, 32), tb, 0, stream>>>(Wo, Wot);

  kmem_cvt<<<(MSLOT * DMODEL) / 256, 256, 0, stream>>>(mk, Kmm);
  vmem_transpose<<<dim3(MSLOT / 32, DMODEL / 32), tb, 0, stream>>>(mv, VtGp);

  gemm_bt<0><<<dim3(16, 32), 256, 0, stream>>>(Qin, Wqt, bq, Qbp);
  gemm_bt<0><<<dim3(16, 32), 256, 0, stream>>>(Kin, Wkt, bk, Kprp);
  gemm_bt_vt<<<dim3(64, 8), 256, 0, stream>>>(Vin, Wvt, bv, VtGp);

  attn_kernel<<<dim3(16, 16, 4), 256, 0, stream>>>(Qbp, Kprp, Kmm, VtGp, Aoutp);

  gemm_bt<1><<<dim3(16, 32), 256, 0, stream>>>(Aoutp, Wot, bo, d_out);
}

// Round 2
// 258.550 us; speedup vs baseline: 1.1656x; 1.1656x over previous
//
#include <hip/hip_runtime.h>

typedef __attribute__((ext_vector_type(8))) __bf16 bf16x8;
typedef __attribute__((ext_vector_type(4))) float f32x4;

#define DEVINL __device__ __forceinline__

constexpr int BZ = 4;
constexpr int SEQ = 1024;
constexpr int DMODEL = 1024;
constexpr int NH = 16;
constexpr int HD = 64;               // dk = dv = 64
constexpr int MSLOT = 128;
constexpr int NT = BZ * SEQ;         // 4096 tokens
constexpr int SKM = SEQ + MSLOT;     // 1152 keys per batch
constexpr int VT_LD = BZ * SKM;      // 4608: leading dim of global V^T
constexpr float SCALE_M = 11.313708498984761f;   // sqrt(128)
constexpr float SCEXP = 0.18033688011112042f;    // (1/sqrt(dk)) * log2(e)
// workspace offsets in bf16 (ushort) elements
constexpr size_t OF_QIN  = 0;
constexpr size_t OF_KIN  = OF_QIN  + (size_t)NT * DMODEL;
constexpr size_t OF_VIN  = OF_KIN  + (size_t)NT * DMODEL;
constexpr size_t OF_WQT  = OF_VIN  + (size_t)NT * DMODEL;
constexpr size_t OF_WKT  = OF_WQT  + (size_t)DMODEL * DMODEL;
constexpr size_t OF_WVT  = OF_WKT  + (size_t)DMODEL * DMODEL;
constexpr size_t OF_WOT  = OF_WVT  + (size_t)DMODEL * DMODEL;
constexpr size_t OF_QB   = OF_WOT  + (size_t)DMODEL * DMODEL;
constexpr size_t OF_KPR  = OF_QB   + (size_t)NT * DMODEL;
constexpr size_t OF_KMEM = OF_KPR  + (size_t)NT * DMODEL;
constexpr size_t OF_VTG  = OF_KMEM + (size_t)MSLOT * DMODEL;
constexpr size_t OF_AOUT = OF_VTG  + (size_t)DMODEL * VT_LD;

DEVINL unsigned short f2bf(float f) {
  union { float f; unsigned u; } v; v.f = f;
  unsigned r = v.u + 0x7FFF + ((v.u >> 16) & 1);   // RNE
  return (unsigned short)(r >> 16);
}

#if __has_builtin(__builtin_amdgcn_cvt_pk_bf16_f32)
DEVINL unsigned pack2(float a, float b) {
  auto t = __builtin_amdgcn_cvt_pk_bf16_f32(a, b);
  unsigned r; __builtin_memcpy(&r, &t, 4); return r;
}
#else
DEVINL unsigned pack2(float a, float b) {
  return (unsigned)f2bf(a) | ((unsigned)f2bf(b) << 16);
}
#endif

#if __has_builtin(__builtin_amdgcn_exp2f)
DEVINL float fast_exp2(float x) { return __builtin_amdgcn_exp2f(x); }
#else
DEVINL float fast_exp2(float x) { return exp2f(x); }
#endif

DEVINL f32x4 mfma16(bf16x8 a, bf16x8 b, f32x4 c) {
  return __builtin_amdgcn_mfma_f32_16x16x32_bf16(a, b, c, 0, 0, 0);
}

// async global -> LDS, 16 bytes per lane (global_load_lds_dwordx4)
DEVINL void gload16(const unsigned short* gp, unsigned short* lp) {
  __builtin_amdgcn_global_load_lds(
      (const __attribute__((address_space(1))) unsigned int*)(const void*)gp,
      (__attribute__((address_space(3))) unsigned int*)(void*)lp, 16, 0, 0);
}

// ---------------- conversion kernels ----------------

// Q/K/V fp32 -> bf16, merged: blockIdx.y selects tensor
__global__ __launch_bounds__(256) void cvt3_bf16(const float* __restrict__ q,
                                                 const float* __restrict__ k,
                                                 const float* __restrict__ v,
                                                 unsigned short* __restrict__ dq,
                                                 unsigned short* __restrict__ dk,
                                                 unsigned short* __restrict__ dv) {
  const float* src = (blockIdx.y == 0) ? q : (blockIdx.y == 1) ? k : v;
  unsigned short* dst = (blockIdx.y == 0) ? dq : (blockIdx.y == 1) ? dk : dv;
  int i = (blockIdx.x * 256 + threadIdx.x) * 8;
  float4 v0 = *(const float4*)(src + i);
  float4 v1 = *(const float4*)(src + i + 4);
  union { unsigned u2[4]; uint4 v; } o;
  o.u2[0] = pack2(v0.x, v0.y); o.u2[1] = pack2(v0.z, v0.w);
  o.u2[2] = pack2(v1.x, v1.y); o.u2[3] = pack2(v1.z, v1.w);
  *(uint4*)(dst + i) = o.v;
}

// W [K=1024][N=1024] fp32 -> Wt [N][K] bf16 (tiled transpose), z selects matrix
__global__ __launch_bounds__(256) void transpose_cvt4(
    const float* __restrict__ s0, const float* __restrict__ s1,
    const float* __restrict__ s2, const float* __restrict__ s3,
    unsigned short* __restrict__ d0, unsigned short* __restrict__ d1,
    unsigned short* __restrict__ d2, unsigned short* __restrict__ d3) {
  const float* src = (blockIdx.z == 0) ? s0 : (blockIdx.z == 1) ? s1 : (blockIdx.z == 2) ? s2 : s3;
  unsigned short* dst = (blockIdx.z == 0) ? d0 : (blockIdx.z == 1) ? d1 : (blockIdx.z == 2) ? d2 : d3;
  __shared__ float t[32][33];
  const int tx = threadIdx.x, ty = threadIdx.y;
  const int n0 = blockIdx.x * 32, k0 = blockIdx.y * 32;
#pragma unroll
  for (int r = 0; r < 4; ++r)
    t[ty + r * 8][tx] = src[(size_t)(k0 + ty + r * 8) * DMODEL + n0 + tx];
  __syncthreads();
#pragma unroll
  for (int r = 0; r < 4; ++r)
    dst[(size_t)(n0 + ty + r * 8) * DMODEL + k0 + tx] = f2bf(t[tx][ty + r * 8]);
}

// Kmem[j][c] = bf16(mk[j][c] * sqrt(M))
__global__ __launch_bounds__(256) void kmem_cvt(const float* __restrict__ mk,
                                                unsigned short* __restrict__ dst) {
  int i = blockIdx.x * 256 + threadIdx.x;
  dst[i] = f2bf(mk[i] * SCALE_M);
}

// mv [128][1024] -> VtG[c][b*1152 + 1024 + j] = bf16(mv[j][c]*sqrt(M))
__global__ __launch_bounds__(256) void vmem_transpose(const float* __restrict__ mv,
                                                      unsigned short* __restrict__ VtG) {
  __shared__ float t[32][33];
  const int tx = threadIdx.x, ty = threadIdx.y;
  const int j0 = blockIdx.x * 32, c0 = blockIdx.y * 32;
#pragma unroll
  for (int r = 0; r < 4; ++r)
    t[ty + r * 8][tx] = mv[(size_t)(j0 + ty + r * 8) * DMODEL + c0 + tx];
  __syncthreads();
#pragma unroll
  for (int r = 0; r < 4; ++r) {
    int c = c0 + ty + r * 8;
    unsigned short v = f2bf(t[tx][ty + r * 8] * SCALE_M);
#pragma unroll
    for (int bb = 0; bb < BZ; ++bb)
      VtG[(size_t)c * VT_LD + bb * SKM + SEQ + j0 + tx] = v;
  }
}

// ---------------- GEMM: C[M][1024] = A[M][1024] @ Wt[n][k]^T + bias ----------------
// BM=128 BN=64 BK=32, 4 waves 2x2, async global_load_lds staging (unpadded rows).
template <int OUT_F32>
__global__ __launch_bounds__(256) void gemm_bt(const unsigned short* __restrict__ A,
                                               const unsigned short* __restrict__ Wt,
                                               const float* __restrict__ bias,
                                               void* __restrict__ Cout) {
  __shared__ unsigned short As[128 * 32];
  __shared__ unsigned short Bs[64 * 32];
  const int tid = threadIdx.x;
  const int m0 = blockIdx.y * 128;
  const int n0 = blockIdx.x * 64;
  const int w = tid >> 6, lane = tid & 63, quad = lane >> 4, l16 = lane & 15;
  const int wr = w >> 1, wc = w & 1;
  f32x4 acc[4][2] = {};
  for (int kt = 0; kt < 32; ++kt) {
    const int k0 = kt * 32;
#pragma unroll
    for (int gi = 0; gi < 2; ++gi) {
      int g = gi * 256 + tid;               // A tile: 512 granules of 16B
      int row = g >> 2, slot = g & 3;
      gload16(A + (size_t)(m0 + row) * DMODEL + k0 + slot * 8, As + g * 8);
    }
    {
      int row = tid >> 2, slot = tid & 3;   // B tile: 256 granules
      gload16(Wt + (size_t)(n0 + row) * DMODEL + k0 + slot * 8, Bs + tid * 8);
    }
    __syncthreads();
    bf16x8 af[4], bfr[2];
#pragma unroll
    for (int rb = 0; rb < 4; ++rb)
      af[rb] = *(const bf16x8*)(As + (wr * 64 + rb * 16 + l16) * 32 + quad * 8);
#pragma unroll
    for (int cb = 0; cb < 2; ++cb)
      bfr[cb] = *(const bf16x8*)(Bs + (wc * 32 + cb * 16 + l16) * 32 + quad * 8);
#pragma unroll
    for (int rb = 0; rb < 4; ++rb)
#pragma unroll
      for (int cb = 0; cb < 2; ++cb)
        acc[rb][cb] = mfma16(af[rb], bfr[cb], acc[rb][cb]);
    __syncthreads();
  }
#pragma unroll
  for (int rb = 0; rb < 4; ++rb)
#pragma unroll
    for (int cb = 0; cb < 2; ++cb)
#pragma unroll
      for (int r = 0; r < 4; ++r) {
        int row = m0 + wr * 64 + rb * 16 + quad * 4 + r;   // D: row=(lane>>4)*4+reg
        int col = n0 + wc * 32 + cb * 16 + l16;            //    col=lane&15
        float v = acc[rb][cb][r] + bias[col];
        if (OUT_F32) ((float*)Cout)[(size_t)row * DMODEL + col] = v;
        else ((unsigned short*)Cout)[(size_t)row * DMODEL + col] = f2bf(v);
      }
}

// V projection writing V^T (A-operand = Wvt rows, B-operand = token rows)
__global__ __launch_bounds__(256) void gemm_bt_vt(const unsigned short* __restrict__ A,
                                                  const unsigned short* __restrict__ Wt,
                                                  const float* __restrict__ bias,
                                                  unsigned short* __restrict__ VtG) {
  __shared__ unsigned short Ts[64 * 32];    // token rows
  __shared__ unsigned short Ns[128 * 32];   // n rows
  const int tid = threadIdx.x;
  const int t0 = blockIdx.x * 64;           // token tile
  const int n0 = blockIdx.y * 128;          // n tile
  const int w = tid >> 6, lane = tid & 63, quad = lane >> 4, l16 = lane & 15;
  const int wr = w >> 1, wc = w & 1;
  f32x4 acc[4][2] = {};
  for (int kt = 0; kt < 32; ++kt) {
    const int k0 = kt * 32;
    {
      int row = tid >> 2, slot = tid & 3;
      gload16(A + (size_t)(t0 + row) * DMODEL + k0 + slot * 8, Ts + tid * 8);
    }
#pragma unroll
    for (int gi = 0; gi < 2; ++gi) {
      int g = gi * 256 + tid;
      int row = g >> 2, slot = g & 3;
      gload16(Wt + (size_t)(n0 + row) * DMODEL + k0 + slot * 8, Ns + g * 8);
    }
    __syncthreads();
    bf16x8 af[4], bfr[2];
#pragma unroll
    for (int rb = 0; rb < 4; ++rb)
      af[rb] = *(const bf16x8*)(Ns + (wr * 64 + rb * 16 + l16) * 32 + quad * 8);
#pragma unroll
    for (int cb = 0; cb < 2; ++cb)
      bfr[cb] = *(const bf16x8*)(Ts + (wc * 32 + cb * 16 + l16) * 32 + quad * 8);
#pragma unroll
    for (int rb = 0; rb < 4; ++rb)
#pragma unroll
      for (int cb = 0; cb < 2; ++cb)
        acc[rb][cb] = mfma16(af[rb], bfr[cb], acc[rb][cb]);
    __syncthreads();
  }
#pragma unroll
  for (int rb = 0; rb < 4; ++rb)
#pragma unroll
    for (int cb = 0; cb < 2; ++cb)
#pragma unroll
      for (int r = 0; r < 4; ++r) {
        int n = n0 + wr * 64 + rb * 16 + quad * 4 + r;
        int tok = t0 + wc * 32 + cb * 16 + l16;
        int col = tok + (tok >> 10) * MSLOT;   // batch-concat column remap
        VtG[(size_t)n * VT_LD + col] = f2bf(acc[rb][cb][r] + bias[n]);
      }
}

// ---------------- flash attention, fixed-max softmax, S^T layout ----------------
// grid (qb=16, h=16, b=4), 4 waves, 64 q/block (16 per wave, q = lane&15).
__global__ __launch_bounds__(256) void attn_kernel(const unsigned short* __restrict__ Qb,
                                                   const unsigned short* __restrict__ Kproj,
                                                   const unsigned short* __restrict__ Kmem,
                                                   const unsigned short* __restrict__ VtG,
                                                   unsigned short* __restrict__ Aout) {
  __shared__ unsigned short Ks[64 * 72];        // [key][kd], stride 72
  __shared__ unsigned short Vs[64 * 72];        // [dv][key] (V^T tile)
  __shared__ unsigned short Pl[4 * 16 * 72];    // per-wave P[q][key]
  const int tid = threadIdx.x;
  const int qb = blockIdx.x, h = blockIdx.y, b = blockIdx.z;
  const int w = tid >> 6, lane = tid & 63, quad = lane >> 4, l16 = lane & 15;
  const int token0 = b * SEQ + qb * 64 + w * 16;
  unsigned short* Pw = Pl + w * 16 * 72;

  bf16x8 qf[2];   // B-operand: Q[n=l16][k = quad*8+j (+32t)]
#pragma unroll
  for (int t = 0; t < 2; ++t)
    qf[t] = *(const bf16x8*)(Qb + (size_t)(token0 + l16) * DMODEL + h * HD + t * 32 + quad * 8);

  f32x4 O[4] = {};
  float lsum = 0.0f;   // per-lane partial of l[q=l16]

  for (int tile = 0; tile < 18; ++tile) {
    const unsigned short* ksrc;
    const unsigned short* vsrc;
    if (tile < 16) {
      ksrc = Kproj + (size_t)(b * SEQ + tile * 64) * DMODEL + h * HD;
      vsrc = VtG + (size_t)(h * HD) * VT_LD + b * SKM + tile * 64;
    } else {
      ksrc = Kmem + (size_t)((tile - 16) * 64) * DMODEL + h * HD;
      vsrc = VtG + (size_t)(h * HD) * VT_LD + b * SKM + SEQ + (tile - 16) * 64;
    }
#pragma unroll
    for (int gi = 0; gi < 2; ++gi) {
      int g = tid + gi * 256;
      int row = g >> 3, slot = g & 7;
      *(uint4*)(Ks + row * 72 + slot * 8) = *(const uint4*)(ksrc + (size_t)row * DMODEL + slot * 8);
      *(uint4*)(Vs + row * 72 + slot * 8) = *(const uint4*)(vsrc + (size_t)row * VT_LD + slot * 8);
    }
    __syncthreads();

    // S^T: A = K rows, B = Q rows. Chunk c: keys c*16..+15 (row = quad*4+r), col = q = l16.
    f32x4 sc[4] = {};
#pragma unroll
    for (int c = 0; c < 4; ++c)
#pragma unroll
      for (int t = 0; t < 2; ++t) {
        bf16x8 kb = *(const bf16x8*)(Ks + (c * 16 + l16) * 72 + t * 32 + quad * 8);
        sc[c] = mfma16(kb, qf[t], sc[c]);
      }

    // fixed-max softmax: p = 2^(s * scale*log2e); l accumulated per-lane, reduced at end
#pragma unroll
    for (int c = 0; c < 4; ++c) {
      float p0 = fast_exp2(sc[c][0] * SCEXP);
      float p1 = fast_exp2(sc[c][1] * SCEXP);
      float p2 = fast_exp2(sc[c][2] * SCEXP);
      float p3 = fast_exp2(sc[c][3] * SCEXP);
      lsum += (p0 + p1) + (p2 + p3);
      union { unsigned u[2]; } pk;
      pk.u[0] = pack2(p0, p1);
      pk.u[1] = pack2(p2, p3);
      // P[q=l16][key = c*16 + quad*4 + 0..3] -> 8B packed write
      *(uint2*)(Pw + l16 * 72 + c * 16 + quad * 4) = *(uint2*)pk.u;
    }
    __builtin_amdgcn_wave_barrier();   // order DS write -> DS read (wave-local)

#pragma unroll
    for (int t2 = 0; t2 < 2; ++t2) {
      bf16x8 pa = *(const bf16x8*)(Pw + l16 * 72 + t2 * 32 + quad * 8);
#pragma unroll
      for (int c2 = 0; c2 < 4; ++c2) {
        bf16x8 vb = *(const bf16x8*)(Vs + (c2 * 16 + l16) * 72 + t2 * 32 + quad * 8);
        O[c2] = mfma16(pa, vb, O[c2]);
      }
    }
    __syncthreads();
  }

  // l[q=l16] = reduce across quad groups (once, after all tiles)
  lsum += __shfl_xor(lsum, 16);
  lsum += __shfl_xor(lsum, 32);
  // output rows are q = quad*4 + r; fetch matching l via width-16 shuffle
#pragma unroll
  for (int r = 0; r < 4; ++r) {
    float lv = __shfl(lsum, quad * 4 + r, 16);
    float inv = 1.0f / lv;
#pragma unroll
    for (int c2 = 0; c2 < 4; ++c2)
      Aout[(size_t)(token0 + quad * 4 + r) * DMODEL + h * HD + c2 * 16 + l16] =
          f2bf(O[c2][r] * inv);
  }
}

// ---------------- launch ----------------
extern "C" void kernel_launch(void* const* d_in, const int* in_sizes, int n_in,
                              void* d_out, int out_size, void* d_ws, size_t ws_size,
                              hipStream_t stream) {
  const float* queries = (const float*)d_in[0];
  const float* keys    = (const float*)d_in[1];
  const float* values  = (const float*)d_in[2];
  const float* Wq = (const float*)d_in[3];
  const float* bq = (const float*)d_in[4];
  const float* Wk = (const float*)d_in[5];
  const float* bk = (const float*)d_in[6];
  const float* Wv = (const float*)d_in[7];
  const float* bv = (const float*)d_in[8];
  const float* Wo = (const float*)d_in[9];
  const float* bo = (const float*)d_in[10];
  const float* mk = (const float*)d_in[11];
  const float* mv = (const float*)d_in[12];

  unsigned short* ws = (unsigned short*)d_ws;
  unsigned short* Qin  = ws + OF_QIN;
  unsigned short* Kin  = ws + OF_KIN;
  unsigned short* Vin  = ws + OF_VIN;
  unsigned short* Wqt  = ws + OF_WQT;
  unsigned short* Wkt  = ws + OF_WKT;
  unsigned short* Wvt  = ws + OF_WVT;
  unsigned short* Wot  = ws + OF_WOT;
  unsigned short* Qbp  = ws + OF_QB;
  unsigned short* Kprp = ws + OF_KPR;
  unsigned short* Kmm  = ws + OF_KMEM;
  unsigned short* VtGp = ws + OF_VTG;
  unsigned short* Aoutp = ws + OF_AOUT;

  cvt3_bf16<<<dim3(2048, 3), 256, 0, stream>>>(queries, keys, values, Qin, Kin, Vin);

  dim3 tb(32, 8);
  transpose_cvt4<<<dim3(32, 32, 4), tb, 0, stream>>>(Wq, Wk, Wv, Wo, Wqt, Wkt, Wvt, Wot);

  kmem_cvt<<<(MSLOT * DMODEL) / 256, 256, 0, stream>>>(mk, Kmm);
  vmem_transpose<<<dim3(MSLOT / 32, DMODEL / 32), tb, 0, stream>>>(mv, VtGp);

  gemm_bt<0><<<dim3(16, 32), 256, 0, stream>>>(Qin, Wqt, bq, Qbp);
  gemm_bt<0><<<dim3(16, 32), 256, 0, stream>>>(Kin, Wkt, bk, Kprp);
  gemm_bt_vt<<<dim3(64, 8), 256, 0, stream>>>(Vin, Wvt, bv, VtGp);

  attn_kernel<<<dim3(16, 16, 4), 256, 0, stream>>>(Qbp, Kprp, Kmm, VtGp, Aoutp);

  gemm_bt<1><<<dim3(16, 32), 256, 0, stream>>>(Aoutp, Wot, bo, d_out);
}

// Round 3
// 228.891 us; speedup vs baseline: 1.3166x; 1.1296x over previous
//
#include <hip/hip_runtime.h>

typedef __attribute__((ext_vector_type(8))) __bf16 bf16x8;
typedef __attribute__((ext_vector_type(4))) float f32x4;

#define DEVINL __device__ __forceinline__

constexpr int BZ = 4;
constexpr int SEQ = 1024;
constexpr int DMODEL = 1024;
constexpr int NH = 16;
constexpr int HD = 64;               // dk = dv = 64
constexpr int MSLOT = 128;
constexpr int NT = BZ * SEQ;         // 4096 tokens
constexpr int SKM = SEQ + MSLOT;     // 1152 keys per batch
constexpr int VT_LD = BZ * SKM;      // 4608: leading dim of global V^T
constexpr float SCALE_M = 11.313708498984761f;   // sqrt(128)
constexpr float SCEXP = 0.18033688011112042f;    // (1/sqrt(dk)) * log2(e)
// workspace offsets in bf16 (ushort) elements
constexpr size_t OF_QIN  = 0;
constexpr size_t OF_KIN  = OF_QIN  + (size_t)NT * DMODEL;
constexpr size_t OF_VIN  = OF_KIN  + (size_t)NT * DMODEL;
constexpr size_t OF_WQT  = OF_VIN  + (size_t)NT * DMODEL;
constexpr size_t OF_WKT  = OF_WQT  + (size_t)DMODEL * DMODEL;
constexpr size_t OF_WVT  = OF_WKT  + (size_t)DMODEL * DMODEL;
constexpr size_t OF_WOT  = OF_WVT  + (size_t)DMODEL * DMODEL;
constexpr size_t OF_QB   = OF_WOT  + (size_t)DMODEL * DMODEL;
constexpr size_t OF_KPR  = OF_QB   + (size_t)NT * DMODEL;
constexpr size_t OF_KMEM = OF_KPR  + (size_t)NT * DMODEL;
constexpr size_t OF_VTG  = OF_KMEM + (size_t)MSLOT * DMODEL;
constexpr size_t OF_AOUT = OF_VTG  + (size_t)DMODEL * VT_LD;

DEVINL unsigned short f2bf(float f) {
  union { float f; unsigned u; } v; v.f = f;
  unsigned r = v.u + 0x7FFF + ((v.u >> 16) & 1);   // RNE
  return (unsigned short)(r >> 16);
}

#if __has_builtin(__builtin_amdgcn_cvt_pk_bf16_f32)
DEVINL unsigned pack2(float a, float b) {
  auto t = __builtin_amdgcn_cvt_pk_bf16_f32(a, b);
  unsigned r; __builtin_memcpy(&r, &t, 4); return r;
}
#else
DEVINL unsigned pack2(float a, float b) {
  return (unsigned)f2bf(a) | ((unsigned)f2bf(b) << 16);
}
#endif

#if __has_builtin(__builtin_amdgcn_exp2f)
DEVINL float fast_exp2(float x) { return __builtin_amdgcn_exp2f(x); }
#else
DEVINL float fast_exp2(float x) { return exp2f(x); }
#endif

DEVINL f32x4 mfma16(bf16x8 a, bf16x8 b, f32x4 c) {
  return __builtin_amdgcn_mfma_f32_16x16x32_bf16(a, b, c, 0, 0, 0);
}

// async global -> LDS, 16 bytes per lane (global_load_lds_dwordx4)
DEVINL void gload16(const unsigned short* gp, unsigned short* lp) {
  __builtin_amdgcn_global_load_lds(
      (const __attribute__((address_space(1))) unsigned int*)(const void*)gp,
      (__attribute__((address_space(3))) unsigned int*)(void*)lp, 16, 0, 0);
}

// ---------------- conversion kernels ----------------

// Q/K/V fp32 -> bf16, merged: blockIdx.y selects tensor
__global__ __launch_bounds__(256) void cvt3_bf16(const float* __restrict__ q,
                                                 const float* __restrict__ k,
                                                 const float* __restrict__ v,
                                                 unsigned short* __restrict__ dq,
                                                 unsigned short* __restrict__ dk,
                                                 unsigned short* __restrict__ dv) {
  const float* src = (blockIdx.y == 0) ? q : (blockIdx.y == 1) ? k : v;
  unsigned short* dst = (blockIdx.y == 0) ? dq : (blockIdx.y == 1) ? dk : dv;
  int i = (blockIdx.x * 256 + threadIdx.x) * 8;
  float4 v0 = *(const float4*)(src + i);
  float4 v1 = *(const float4*)(src + i + 4);
  union { unsigned u2[4]; uint4 v; } o;
  o.u2[0] = pack2(v0.x, v0.y); o.u2[1] = pack2(v0.z, v0.w);
  o.u2[2] = pack2(v1.x, v1.y); o.u2[3] = pack2(v1.z, v1.w);
  *(uint4*)(dst + i) = o.v;
}

// W [K=1024][N=1024] fp32 -> Wt [N][K] bf16, vectorized 16B stores.
// tile: 32 n-cols x 64 k-rows. z selects matrix.
__global__ __launch_bounds__(256) void transpose_cvt4(
    const float* __restrict__ s0, const float* __restrict__ s1,
    const float* __restrict__ s2, const float* __restrict__ s3,
    unsigned short* __restrict__ d0, unsigned short* __restrict__ d1,
    unsigned short* __restrict__ d2, unsigned short* __restrict__ d3) {
  const float* src = (blockIdx.z == 0) ? s0 : (blockIdx.z == 1) ? s1 : (blockIdx.z == 2) ? s2 : s3;
  unsigned short* dst = (blockIdx.z == 0) ? d0 : (blockIdx.z == 1) ? d1 : (blockIdx.z == 2) ? d2 : d3;
  __shared__ float t[32][65];
  const int tid = threadIdx.x;
  const int n0 = blockIdx.x * 32, k0 = blockIdx.y * 64;
  {
    int c = tid & 31, rg = tid >> 5;      // 8 rows per row-group
#pragma unroll
    for (int rr = 0; rr < 8; ++rr)
      t[c][rg * 8 + rr] = src[(size_t)(k0 + rg * 8 + rr) * DMODEL + n0 + c];
  }
  __syncthreads();
  {
    int n = tid >> 3, ck = tid & 7;
    union { unsigned short u[8]; uint4 v; } o;
#pragma unroll
    for (int j = 0; j < 8; ++j) o.u[j] = f2bf(t[n][ck * 8 + j]);
    *(uint4*)(dst + (size_t)(n0 + n) * DMODEL + k0 + ck * 8) = o.v;
  }
}

// Kmem[j][c] = bf16(mk[j][c] * sqrt(M))
__global__ __launch_bounds__(256) void kmem_cvt(const float* __restrict__ mk,
                                                unsigned short* __restrict__ dst) {
  int i = blockIdx.x * 256 + threadIdx.x;
  dst[i] = f2bf(mk[i] * SCALE_M);
}

// mv [128][1024] -> VtG[c][b*1152 + 1024 + j] = bf16(mv[j][c]*sqrt(M))
__global__ __launch_bounds__(256) void vmem_transpose(const float* __restrict__ mv,
                                                      unsigned short* __restrict__ VtG) {
  __shared__ float t[32][33];
  const int tx = threadIdx.x, ty = threadIdx.y;
  const int j0 = blockIdx.x * 32, c0 = blockIdx.y * 32;
#pragma unroll
  for (int r = 0; r < 4; ++r)
    t[ty + r * 8][tx] = mv[(size_t)(j0 + ty + r * 8) * DMODEL + c0 + tx];
  __syncthreads();
#pragma unroll
  for (int r = 0; r < 4; ++r) {
    int c = c0 + ty + r * 8;
    unsigned short v = f2bf(t[tx][ty + r * 8] * SCALE_M);
#pragma unroll
    for (int bb = 0; bb < BZ; ++bb)
      VtG[(size_t)c * VT_LD + bb * SKM + SEQ + j0 + tx] = v;
  }
}

// ---------------- GEMM core (BK=64, split column-half buffers, BM=128 BN=64) ----
// big = 128-row operand, sm = 64-row operand, both k-contiguous (N x K layout).
// Rows in LDS keep stride 32 ushorts (the m97-proven pattern for global_load_lds).

DEVINL void gemm_stage(const unsigned short* big, const unsigned short* sm,
                       unsigned short* B0, unsigned short* B1,
                       unsigned short* S0, unsigned short* S1,
                       int k0, int tid) {
#pragma unroll
  for (int hb = 0; hb < 2; ++hb) {
    unsigned short* bl = hb ? B1 : B0;
#pragma unroll
    for (int gi = 0; gi < 2; ++gi) {
      int g = gi * 256 + tid;
      int row = g >> 2, slot = g & 3;
      gload16(big + (size_t)row * DMODEL + k0 + hb * 32 + slot * 8, bl + g * 8);
    }
    unsigned short* sl = hb ? S1 : S0;
    int row = tid >> 2, slot = tid & 3;
    gload16(sm + (size_t)row * DMODEL + k0 + hb * 32 + slot * 8, sl + tid * 8);
  }
}

DEVINL void gemm_compute(const unsigned short* B0, const unsigned short* B1,
                         const unsigned short* S0, const unsigned short* S1,
                         int wr, int wc, int quad, int l16, f32x4 acc[4][2]) {
#pragma unroll
  for (int hb = 0; hb < 2; ++hb) {
    const unsigned short* bl = hb ? B1 : B0;
    const unsigned short* sl = hb ? S1 : S0;
    bf16x8 af[4], bfr[2];
#pragma unroll
    for (int rb = 0; rb < 4; ++rb)
      af[rb] = *(const bf16x8*)(bl + (wr * 64 + rb * 16 + l16) * 32 + quad * 8);
#pragma unroll
    for (int cb = 0; cb < 2; ++cb)
      bfr[cb] = *(const bf16x8*)(sl + (wc * 32 + cb * 16 + l16) * 32 + quad * 8);
#pragma unroll
    for (int rb = 0; rb < 4; ++rb)
#pragma unroll
      for (int cb = 0; cb < 2; ++cb)
        acc[rb][cb] = mfma16(af[rb], bfr[cb], acc[rb][cb]);
  }
}

// merged Q/K/V projections: blocks [0,512) Q, [512,1024) K, [1024,1536) V^T
__global__ __launch_bounds__(256) void proj_qkv(
    const unsigned short* __restrict__ Qin, const unsigned short* __restrict__ Kin,
    const unsigned short* __restrict__ Vin, const unsigned short* __restrict__ Wqt,
    const unsigned short* __restrict__ Wkt, const unsigned short* __restrict__ Wvt,
    const float* __restrict__ bq, const float* __restrict__ bk,
    const float* __restrict__ bv, unsigned short* __restrict__ Qbp,
    unsigned short* __restrict__ Kprp, unsigned short* __restrict__ VtG) {
  __shared__ unsigned short Big0[128 * 32], Big1[128 * 32];
  __shared__ unsigned short Sm0[64 * 32], Sm1[64 * 32];
  const int tid = threadIdx.x;
  const int pid = blockIdx.x >> 9;
  const int idx = blockIdx.x & 511;
  const int w = tid >> 6, lane = tid & 63, quad = lane >> 4, l16 = lane & 15;
  const int wr = w >> 1, wc = w & 1;
  f32x4 acc[4][2] = {};

  if (pid < 2) {
    const unsigned short* A  = pid ? Kin : Qin;
    const unsigned short* Wt = pid ? Wkt : Wqt;
    const float* bias        = pid ? bk : bq;
    unsigned short* out      = pid ? Kprp : Qbp;
    const int n0 = (idx & 15) * 64, m0 = (idx >> 4) * 128;
    const unsigned short* big = A + (size_t)m0 * DMODEL;
    const unsigned short* sm  = Wt + (size_t)n0 * DMODEL;
    for (int kt = 0; kt < 16; ++kt) {
      gemm_stage(big, sm, Big0, Big1, Sm0, Sm1, kt * 64, tid);
      __syncthreads();
      gemm_compute(Big0, Big1, Sm0, Sm1, wr, wc, quad, l16, acc);
      __syncthreads();
    }
#pragma unroll
    for (int rb = 0; rb < 4; ++rb)
#pragma unroll
      for (int cb = 0; cb < 2; ++cb)
#pragma unroll
        for (int r = 0; r < 4; ++r) {
          int row = m0 + wr * 64 + rb * 16 + quad * 4 + r;
          int col = n0 + wc * 32 + cb * 16 + l16;
          out[(size_t)row * DMODEL + col] = f2bf(acc[rb][cb][r] + bias[col]);
        }
  } else {
    const int t0 = (idx & 63) * 64, n0 = (idx >> 6) * 128;
    const unsigned short* big = Wvt + (size_t)n0 * DMODEL;   // n rows
    const unsigned short* sm  = Vin + (size_t)t0 * DMODEL;   // token rows
    for (int kt = 0; kt < 16; ++kt) {
      gemm_stage(big, sm, Big0, Big1, Sm0, Sm1, kt * 64, tid);
      __syncthreads();
      gemm_compute(Big0, Big1, Sm0, Sm1, wr, wc, quad, l16, acc);
      __syncthreads();
    }
#pragma unroll
    for (int rb = 0; rb < 4; ++rb)
#pragma unroll
      for (int cb = 0; cb < 2; ++cb)
#pragma unroll
        for (int r = 0; r < 4; ++r) {
          int n = n0 + wr * 64 + rb * 16 + quad * 4 + r;
          int tok = t0 + wc * 32 + cb * 16 + l16;
          int col = tok + (tok >> 10) * MSLOT;
          VtG[(size_t)n * VT_LD + col] = f2bf(acc[rb][cb][r] + bv[n]);
        }
  }
}

// output GEMM: C[4096][1024] fp32 = Aout @ Wot^T + bo
__global__ __launch_bounds__(256) void gemm_out(const unsigned short* __restrict__ A,
                                                const unsigned short* __restrict__ Wt,
                                                const float* __restrict__ bias,
                                                float* __restrict__ Cout) {
  __shared__ unsigned short Big0[128 * 32], Big1[128 * 32];
  __shared__ unsigned short Sm0[64 * 32], Sm1[64 * 32];
  const int tid = threadIdx.x;
  const int m0 = blockIdx.y * 128, n0 = blockIdx.x * 64;
  const int w = tid >> 6, lane = tid & 63, quad = lane >> 4, l16 = lane & 15;
  const int wr = w >> 1, wc = w & 1;
  f32x4 acc[4][2] = {};
  const unsigned short* big = A + (size_t)m0 * DMODEL;
  const unsigned short* sm  = Wt + (size_t)n0 * DMODEL;
  for (int kt = 0; kt < 16; ++kt) {
    gemm_stage(big, sm, Big0, Big1, Sm0, Sm1, kt * 64, tid);
    __syncthreads();
    gemm_compute(Big0, Big1, Sm0, Sm1, wr, wc, quad, l16, acc);
    __syncthreads();
  }
#pragma unroll
  for (int rb = 0; rb < 4; ++rb)
#pragma unroll
    for (int cb = 0; cb < 2; ++cb)
#pragma unroll
      for (int r = 0; r < 4; ++r) {
        int row = m0 + wr * 64 + rb * 16 + quad * 4 + r;
        int col = n0 + wc * 32 + cb * 16 + l16;
        Cout[(size_t)row * DMODEL + col] = acc[rb][cb][r] + bias[col];
      }
}

// ---------------- flash attention, fixed-max softmax, S^T layout ----------------
// 1024 blocks 1D; swizzle: i&63 = (b,h) so the 16 q-blocks of one (b,h) land on
// one XCD (round-robin heuristic) and share its L2 K/V slice (~2.3MB < 4MB).
// Register prefetch: tile t+1's K/V global loads issue before tile t's compute.
__global__ __launch_bounds__(256) void attn_kernel(const unsigned short* __restrict__ Qb,
                                                   const unsigned short* __restrict__ Kproj,
                                                   const unsigned short* __restrict__ Kmem,
                                                   const unsigned short* __restrict__ VtG,
                                                   unsigned short* __restrict__ Aout) {
  __shared__ unsigned short Ks[64 * 72];        // [key][kd], stride 72
  __shared__ unsigned short Vs[64 * 72];        // [dv][key] (V^T tile)
  __shared__ unsigned short Pl[4 * 16 * 72];    // per-wave P[q][key]
  const int tid = threadIdx.x;
  const int bh = blockIdx.x & 63, qb = blockIdx.x >> 6;
  const int b = bh & 3, h = bh >> 2;
  const int w = tid >> 6, lane = tid & 63, quad = lane >> 4, l16 = lane & 15;
  const int token0 = b * SEQ + qb * 64 + w * 16;
  unsigned short* Pw = Pl + w * 16 * 72;

  const int g0 = tid, g1 = tid + 256;
  const int row0 = g0 >> 3, slot0 = g0 & 7;
  const int row1 = g1 >> 3, slot1 = g1 & 7;

  auto kbase = [&](int tile) -> const unsigned short* {
    return (tile < 16) ? Kproj + (size_t)(b * SEQ + tile * 64) * DMODEL + h * HD
                       : Kmem + (size_t)((tile - 16) * 64) * DMODEL + h * HD;
  };
  auto vbase = [&](int tile) -> const unsigned short* {
    int c0 = (tile < 16) ? b * SKM + tile * 64 : b * SKM + SEQ + (tile - 16) * 64;
    return VtG + (size_t)(h * HD) * VT_LD + c0;
  };

  bf16x8 qf[2];   // B-operand: Q[n=l16][k = quad*8+j (+32t)]
#pragma unroll
  for (int t = 0; t < 2; ++t)
    qf[t] = *(const bf16x8*)(Qb + (size_t)(token0 + l16) * DMODEL + h * HD + t * 32 + quad * 8);

  f32x4 O[4] = {};
  float lsum = 0.0f;   // per-lane partial of l[q=l16]

  // prefetch tile 0
  uint4 kr0, kr1, vr0, vr1;
  {
    const unsigned short* kp = kbase(0);
    const unsigned short* vp = vbase(0);
    kr0 = *(const uint4*)(kp + (size_t)row0 * DMODEL + slot0 * 8);
    kr1 = *(const uint4*)(kp + (size_t)row1 * DMODEL + slot1 * 8);
    vr0 = *(const uint4*)(vp + (size_t)row0 * VT_LD + slot0 * 8);
    vr1 = *(const uint4*)(vp + (size_t)row1 * VT_LD + slot1 * 8);
  }

  for (int tile = 0; tile < 18; ++tile) {
    // staged regs -> LDS
    *(uint4*)(Ks + row0 * 72 + slot0 * 8) = kr0;
    *(uint4*)(Ks + row1 * 72 + slot1 * 8) = kr1;
    *(uint4*)(Vs + row0 * 72 + slot0 * 8) = vr0;
    *(uint4*)(Vs + row1 * 72 + slot1 * 8) = vr1;
    __syncthreads();
    if (tile < 17) {   // issue next tile's loads; latency hidden by compute below
      const unsigned short* kp = kbase(tile + 1);
      const unsigned short* vp = vbase(tile + 1);
      kr0 = *(const uint4*)(kp + (size_t)row0 * DMODEL + slot0 * 8);
      kr1 = *(const uint4*)(kp + (size_t)row1 * DMODEL + slot1 * 8);
      vr0 = *(const uint4*)(vp + (size_t)row0 * VT_LD + slot0 * 8);
      vr1 = *(const uint4*)(vp + (size_t)row1 * VT_LD + slot1 * 8);
    }

    // S^T: A = K rows, B = Q rows. Chunk c: keys c*16+quad*4+r, col q = l16.
    f32x4 sc[4] = {};
#pragma unroll
    for (int c = 0; c < 4; ++c)
#pragma unroll
      for (int t = 0; t < 2; ++t) {
        bf16x8 kb = *(const bf16x8*)(Ks + (c * 16 + l16) * 72 + t * 32 + quad * 8);
        sc[c] = mfma16(kb, qf[t], sc[c]);
      }

    // fixed-max softmax: p = 2^(s*scale*log2e); l per-lane, reduced once at end
#pragma unroll
    for (int c = 0; c < 4; ++c) {
      float p0 = fast_exp2(sc[c][0] * SCEXP);
      float p1 = fast_exp2(sc[c][1] * SCEXP);
      float p2 = fast_exp2(sc[c][2] * SCEXP);
      float p3 = fast_exp2(sc[c][3] * SCEXP);
      lsum += (p0 + p1) + (p2 + p3);
      union { unsigned u[2]; } pk;
      pk.u[0] = pack2(p0, p1);
      pk.u[1] = pack2(p2, p3);
      *(uint2*)(Pw + l16 * 72 + c * 16 + quad * 4) = *(uint2*)pk.u;
    }
    __builtin_amdgcn_wave_barrier();   // order DS write -> DS read (wave-local)

#pragma unroll
    for (int t2 = 0; t2 < 2; ++t2) {
      bf16x8 pa = *(const bf16x8*)(Pw + l16 * 72 + t2 * 32 + quad * 8);
#pragma unroll
      for (int c2 = 0; c2 < 4; ++c2) {
        bf16x8 vb = *(const bf16x8*)(Vs + (c2 * 16 + l16) * 72 + t2 * 32 + quad * 8);
        O[c2] = mfma16(pa, vb, O[c2]);
      }
    }
    __syncthreads();
  }

  lsum += __shfl_xor(lsum, 16);
  lsum += __shfl_xor(lsum, 32);
#pragma unroll
  for (int r = 0; r < 4; ++r) {
    float lv = __shfl(lsum, quad * 4 + r, 16);
    float inv = 1.0f / lv;
#pragma unroll
    for (int c2 = 0; c2 < 4; ++c2)
      Aout[(size_t)(token0 + quad * 4 + r) * DMODEL + h * HD + c2 * 16 + l16] =
          f2bf(O[c2][r] * inv);
  }
}

// ---------------- launch ----------------
extern "C" void kernel_launch(void* const* d_in, const int* in_sizes, int n_in,
                              void* d_out, int out_size, void* d_ws, size_t ws_size,
                              hipStream_t stream) {
  const float* queries = (const float*)d_in[0];
  const float* keys    = (const float*)d_in[1];
  const float* values  = (const float*)d_in[2];
  const float* Wq = (const float*)d_in[3];
  const float* bq = (const float*)d_in[4];
  const float* Wk = (const float*)d_in[5];
  const float* bk = (const float*)d_in[6];
  const float* Wv = (const float*)d_in[7];
  const float* bv = (const float*)d_in[8];
  const float* Wo = (const float*)d_in[9];
  const float* bo = (const float*)d_in[10];
  const float* mk = (const float*)d_in[11];
  const float* mv = (const float*)d_in[12];

  unsigned short* ws = (unsigned short*)d_ws;
  unsigned short* Qin  = ws + OF_QIN;
  unsigned short* Kin  = ws + OF_KIN;
  unsigned short* Vin  = ws + OF_VIN;
  unsigned short* Wqt  = ws + OF_WQT;
  unsigned short* Wkt  = ws + OF_WKT;
  unsigned short* Wvt  = ws + OF_WVT;
  unsigned short* Wot  = ws + OF_WOT;
  unsigned short* Qbp  = ws + OF_QB;
  unsigned short* Kprp = ws + OF_KPR;
  unsigned short* Kmm  = ws + OF_KMEM;
  unsigned short* VtGp = ws + OF_VTG;
  unsigned short* Aoutp = ws + OF_AOUT;

  cvt3_bf16<<<dim3(2048, 3), 256, 0, stream>>>(queries, keys, values, Qin, Kin, Vin);

  transpose_cvt4<<<dim3(32, 16, 4), 256, 0, stream>>>(Wq, Wk, Wv, Wo, Wqt, Wkt, Wvt, Wot);

  kmem_cvt<<<(MSLOT * DMODEL) / 256, 256, 0, stream>>>(mk, Kmm);
  vmem_transpose<<<dim3(MSLOT / 32, DMODEL / 32), dim3(32, 8), 0, stream>>>(mv, VtGp);

  proj_qkv<<<1536, 256, 0, stream>>>(Qin, Kin, Vin, Wqt, Wkt, Wvt, bq, bk, bv,
                                     Qbp, Kprp, VtGp);

  attn_kernel<<<1024, 256, 0, stream>>>(Qbp, Kprp, Kmm, VtGp, Aoutp);

  gemm_out<<<dim3(16, 32), 256, 0, stream>>>(Aoutp, Wot, bo, (float*)d_out);
}